// Round 9
// baseline (485.139 us; speedup 1.0000x reference)
//
#include <hip/hip_runtime.h>
#include <hip/hip_bf16.h>
#include <float.h>
#include <stdint.h>

// Problem constants
#define NB   64      // batch / num graphs
#define CD   128     // channels / dims
#define OUTD 256
#define NNODE 20000
#define NEDGE 640000

typedef __bf16 bf16x8 __attribute__((ext_vector_type(8)));
typedef __bf16 bf16x4 __attribute__((ext_vector_type(4)));
typedef float  f32x4  __attribute__((ext_vector_type(4)));

__device__ inline void gl_lds16(const void* g, void* l) {
  __builtin_amdgcn_global_load_lds(
      (const __attribute__((address_space(1))) void*)g,
      (__attribute__((address_space(3))) void*)l, 16, 0, 0);
}

// float atomic max via signed/unsigned int monotonic trick (works for mixed signs)
__device__ inline void atomicMaxF(float* addr, float val) {
  if (val >= 0.f) atomicMax((int*)addr, __float_as_int(val));
  else            atomicMin((unsigned int*)addr, __float_as_uint(val));
}

// ---------------- init: pooled buffers (-FLT_MAX), CSR counters (=0), SN scratch (=0) ----------------
// sn_scratch layout: [0..1151]=v0, [1152..1663]=v1, [1664..1791]=v2, [1792..1795]=ss
__global__ void k_init(float* __restrict__ pooled_v, float* __restrict__ pooled_t,
                       int* __restrict__ cnt, int* __restrict__ fill,
                       float* __restrict__ sn_scratch, int* __restrict__ ntotal) {
  const int i = blockIdx.x * 256 + threadIdx.x;   // grid covers 32768
  if (i < NB * CD * 4) pooled_v[i] = -FLT_MAX;
  if (i < NB * CD)     pooled_t[i] = -FLT_MAX;
  if (i < NNODE)       { cnt[i] = 0; fill[i] = 0; }
  if (i < 1796)        sn_scratch[i] = 0.0f;
  if (i == 0)          *ntotal = 0;
}

// ---------------- SN stage 1: v = W^T u, 8-row chunks (80 blocks) ----------------
__global__ __launch_bounds__(256) void k_sn_v(const float* __restrict__ conv_w, const float* __restrict__ conv_u,
                                              const float* __restrict__ fcv_w,  const float* __restrict__ fcv_u,
                                              const float* __restrict__ fct_w,  const float* __restrict__ fct_u,
                                              float* __restrict__ sn) {
  const int bb = blockIdx.x;       // 0..79
  const float* W; const float* u; float* v; int C; int r0;
  if (bb < 16)      { W = conv_w; u = conv_u; v = sn;        C = 1152; r0 = bb * 8; }
  else if (bb < 48) { W = fcv_w;  u = fcv_u;  v = sn + 1152; C = 512;  r0 = (bb - 16) * 8; }
  else              { W = fct_w;  u = fct_u;  v = sn + 1664; C = 128;  r0 = (bb - 48) * 8; }
  const int tid = threadIdx.x;
  float acc[5] = {0.f, 0.f, 0.f, 0.f, 0.f};
  for (int i = r0; i < r0 + 8; ++i) {
    const float ui = u[i];
    const float* row = W + (size_t)i * C;
    #pragma unroll
    for (int t = 0; t < 5; ++t) {
      const int j = tid + t * 256;
      if (j < C) acc[t] += ui * row[j];
    }
  }
  #pragma unroll
  for (int t = 0; t < 5; ++t) {
    const int j = tid + t * 256;
    if (j < C) atomicAdd(&v[j], acc[t]);
  }
}

// ---------------- SN stage 2: ss[m] = ||W v||^2, one wave per row ----------------
__global__ __launch_bounds__(256) void k_sn_w(const float* __restrict__ conv_w,
                                              const float* __restrict__ fcv_w,
                                              const float* __restrict__ fct_w,
                                              float* __restrict__ sn) {
  const int gw = blockIdx.x * 4 + (threadIdx.x >> 6);   // global wave id, 0..639
  const int lane = threadIdx.x & 63;
  const float* W; const float* v; int C, m, row;
  if (gw < 128)      { W = conv_w; v = sn;        C = 1152; m = 0; row = gw; }
  else if (gw < 384) { W = fcv_w;  v = sn + 1152; C = 512;  m = 1; row = gw - 128; }
  else               { W = fct_w;  v = sn + 1664; C = 128;  m = 2; row = gw - 384; }
  const float* wr = W + (size_t)row * C;
  float y = 0.f;
  for (int c = lane; c < C; c += 64) y += wr[c] * v[c];
  #pragma unroll
  for (int s = 32; s > 0; s >>= 1) y += __shfl_xor(y, s, 64);
  if (lane == 0) atomicAdd(&sn[1792 + m], y * y);
}

// ---------------- SN stage 3: inv_sigma[m] = (||v||+eps)/||Wv|| ----------------
__global__ __launch_bounds__(256) void k_sn_fin(const float* __restrict__ sn, float* __restrict__ inv_sigma) {
  __shared__ float red[256];
  const int tid = threadIdx.x;
  const int off[4] = {0, 1152, 1664, 1792};
  for (int m = 0; m < 3; ++m) {
    const int C = off[m + 1] - off[m];
    float ss = 0.f;
    for (int j = tid; j < C; j += 256) { const float a = sn[off[m] + j]; ss += a * a; }
    red[tid] = ss; __syncthreads();
    for (int s = 128; s > 0; s >>= 1) { if (tid < s) red[tid] += red[tid + s]; __syncthreads(); }
    if (tid == 0) inv_sigma[m] = (sqrtf(red[0]) + 1e-12f) / sqrtf(sn[1792 + m]);
    __syncthreads();
  }
}

// ---------------- fused prep: transpose (blocks 0..1023) + pack (1024..1599) + deg (1600..4099) ----------------
// R10 transpose: 2-phase 32KB LDS (c 0..63 then 64..127) -> 4 blocks/CU (was 64KB/2 blocks).
// Reads stay fully-coalesced 1KB per channel (rows y..y+3 contiguous in NCHW).
__global__ __launch_bounds__(256, 4) void k_prep(const float* __restrict__ vis, __bf16* __restrict__ visT2,
                                                 const float* __restrict__ conv_w, const float* __restrict__ inv_sigma,
                                                 __hip_bfloat16* __restrict__ Bt2,
                                                 const int* __restrict__ dst, int* __restrict__ cnt) {
  __shared__ __bf16 tile[16384];          // [cl(64)][f(256)=y'(4)*64+x(64)]  32 KB (transpose branch only)
  const int bid = blockIdx.x;
  const int t = threadIdx.x;
  if (bid < 1024) {
    const int b = bid >> 4, y0 = (bid & 15) << 2;
    const int wave = t >> 6, lane = t & 63;
    const float* src = vis + (size_t)b * 524288 + y0 * 64 + lane * 4;
    #pragma unroll
    for (int ph = 0; ph < 2; ++ph) {
      #pragma unroll
      for (int i = 0; i < 16; ++i) {
        const int cl = wave * 16 + i;                  // local channel 0..63
        const int c = (ph << 6) + cl;
        const f32x4 v = *(const f32x4*)(src + (size_t)c * 4096);
        bf16x4 o;
        #pragma unroll
        for (int k = 0; k < 4; ++k) o[k] = (__bf16)v[k];
        *(bf16x4*)&tile[cl * 256 + lane * 4] = o;
      }
      __syncthreads();
      // write: visT2[b][y0+yy][g=ph*8+gl][x][c8], coalesced 16B/lane stores
      #pragma unroll
      for (int yy = 0; yy < 4; ++yy) {
        bf16x8* dstv = (bf16x8*)(visT2 + ((size_t)((b << 6) + y0 + yy) << 13)) + (ph << 9);
        #pragma unroll
        for (int k = 0; k < 2; ++k) {
          const int j = k * 256 + t;        // gl = j>>6 (0..7), x = j&63
          const int gl = j >> 6, x = j & 63;
          union { bf16x8 v; __bf16 h[8]; } u;
          #pragma unroll
          for (int cc = 0; cc < 8; ++cc)
            u.h[cc] = tile[(gl * 8 + cc) * 256 + yy * 64 + x];
          dstv[j] = u.v;
        }
      }
      if (ph == 0) __syncthreads();
    }
  } else if (bid < 1600) {
    // Bt2[tap(9)][halfk(2)][sub(8)][n(128)][c8(8)] = conv_w[n][ci=hk*64+s*8+j][tap] / sigma
    const int tt = (bid - 1024) * 256 + t;
    if (tt < 147456) {
      const int j = tt & 7, n = (tt >> 3) & 127, s = (tt >> 10) & 7, hk = (tt >> 13) & 1, tap = tt >> 14;
      const int ci = hk * 64 + s * 8 + j;
      Bt2[tt] = __float2bfloat16(conv_w[n * 1152 + ci * 9 + tap] * inv_sigma[0]);
    }
  } else {
    const int e = (bid - 1600) * 256 + t;
    if (e < NEDGE) atomicAdd(&cnt[dst[e]], 1);
  }
}

// ---------------- fused conv3x3 + bias + leaky + 31x31 maxpool (implicit GEMM, bf16 MFMA) ----------------
// R4 structure (proven ~92us full / ~47us per half). Split into 2 half-batch dispatches for top-5
// visibility. R8's bucket fusion was neutral (+22us on dispatch, write-amp) -> unfused again.
__global__ __launch_bounds__(256, 4) void k_conv(const __hip_bfloat16* __restrict__ visT2,
                                                 const __hip_bfloat16* __restrict__ Bt2,
                                                 const float* __restrict__ conv_b,
                                                 float* __restrict__ pooled_v, int b0) {
  __shared__ bf16x8 lds_a[1024];   // 16 KB  [sub(8)][m(128)]
  __shared__ bf16x8 lds_b[1024];   // 16 KB  [sub(8)][n(128)]
  const int bx = blockIdx.x;
  const int b = b0 + bx / 31;
  const int y0 = (bx % 31) * 2;
  const int tid = threadIdx.x;
  const int wave = tid >> 6, lane = tid & 63;
  const int quad = lane >> 4, l15 = lane & 15;

  f32x4 acc[8][2];
  #pragma unroll
  for (int i = 0; i < 8; ++i) {
    acc[i][0] = f32x4{0.f, 0.f, 0.f, 0.f};
    acc[i][1] = f32x4{0.f, 0.f, 0.f, 0.f};
  }

  const __hip_bfloat16* vb = visT2 + ((size_t)b << 19);   // b*64*16*512
  const int s0 = wave << 1;                 // this wave stages subchunks s0, s0+1
  bf16x8* ldsA0 = &lds_a[s0 << 7];
  bf16x8* ldsB0 = &lds_b[s0 << 7];
  const int lane8 = lane << 3;

  for (int ky = 0; ky < 3; ++ky) {
    for (int kx = 0; kx < 3; ++kx) {
      const int tap = ky * 3 + kx;
      #pragma unroll
      for (int hk = 0; hk < 2; ++hk) {
        // A: visT2 row-group (y, g=hk*8+s); kx shift = +kx*8 elems; lanes contiguous.
        const __hip_bfloat16* a0p = vb + ((size_t)(((y0 + ky) << 4) + (hk << 3) + s0) << 9) + (kx << 3) + lane8;
        const __hip_bfloat16* a1p = vb + ((size_t)(((y0 + 1 + ky) << 4) + (hk << 3) + s0) << 9) + (kx << 3) + lane8;
        const __hip_bfloat16* bp  = Bt2 + (((size_t)(((tap << 1) + hk) << 3) + s0) << 10) + lane8;
        gl_lds16(a0p,        ldsA0);         // sub s0, m 0..63   (row0)
        gl_lds16(a1p,        ldsA0 + 64);    // sub s0, m 64..127 (row1)
        gl_lds16(a0p + 512,  ldsA0 + 128);   // sub s0+1, row0
        gl_lds16(a1p + 512,  ldsA0 + 192);   // sub s0+1, row1
        gl_lds16(bp,         ldsB0);         // sub s0, n 0..63
        gl_lds16(bp + 512,   ldsB0 + 64);    // sub s0, n 64..127
        gl_lds16(bp + 1024,  ldsB0 + 128);   // sub s0+1, n 0..63
        gl_lds16(bp + 1536,  ldsB0 + 192);   // sub s0+1, n 64..127
        __syncthreads();
        const bf16x8 b00 = lds_b[(quad << 7) + (wave << 5) + l15];
        const bf16x8 b01 = lds_b[(quad << 7) + (wave << 5) + 16 + l15];
        const bf16x8 b10 = lds_b[((4 + quad) << 7) + (wave << 5) + l15];
        const bf16x8 b11 = lds_b[((4 + quad) << 7) + (wave << 5) + 16 + l15];
        #pragma unroll
        for (int mt = 0; mt < 8; ++mt) {
          const bf16x8 a0 = lds_a[(quad << 7) + (mt << 4) + l15];
          const bf16x8 a1 = lds_a[((4 + quad) << 7) + (mt << 4) + l15];
          acc[mt][0] = __builtin_amdgcn_mfma_f32_16x16x32_bf16(a0, b00, acc[mt][0], 0, 0, 0);
          acc[mt][1] = __builtin_amdgcn_mfma_f32_16x16x32_bf16(a0, b01, acc[mt][1], 0, 0, 0);
          acc[mt][0] = __builtin_amdgcn_mfma_f32_16x16x32_bf16(a1, b10, acc[mt][0], 0, 0, 0);
          acc[mt][1] = __builtin_amdgcn_mfma_f32_16x16x32_bf16(a1, b11, acc[mt][1], 0, 0, 0);
        }
        __syncthreads();
      }
    }
  }

  // epilogue: bias + leaky + pool-max. C layout: n = nbase + l15, m = mt*16 + quad*4 + r.
  const float cb0 = conv_b[(wave << 5) + l15];
  const float cb1 = conv_b[(wave << 5) + 16 + l15];
  float pmax[2][2][2];
  #pragma unroll
  for (int i = 0; i < 8; ++i) (&pmax[0][0][0])[i] = -FLT_MAX;

  #pragma unroll
  for (int mt = 0; mt < 8; ++mt) {
    const int py = (y0 + (mt >> 2)) >= 31 ? 1 : 0;
    #pragma unroll
    for (int r = 0; r < 4; ++r) {
      const int x = ((mt & 3) << 4) + (quad << 2) + r;
      if (x < 62) {
        const int px = x >= 31 ? 1 : 0;
        float v0 = acc[mt][0][r] + cb0;  v0 = v0 >= 0.f ? v0 : 0.2f * v0;
        float v1 = acc[mt][1][r] + cb1;  v1 = v1 >= 0.f ? v1 : 0.2f * v1;
        pmax[0][py][px] = fmaxf(pmax[0][py][px], v0);
        pmax[1][py][px] = fmaxf(pmax[1][py][px], v1);
      }
    }
  }
  #pragma unroll
  for (int nt = 0; nt < 2; ++nt)
    #pragma unroll
    for (int py = 0; py < 2; ++py)
      #pragma unroll
      for (int px = 0; px < 2; ++px) {
        float v = pmax[nt][py][px];
        v = fmaxf(v, __shfl_xor(v, 16, 64));
        v = fmaxf(v, __shfl_xor(v, 32, 64));
        if (quad == 0) {
          const int n = (wave << 5) + (nt << 4) + l15;
          atomicMaxF(&pooled_v[(size_t)b * 512 + n * 4 + py * 2 + px], v);
        }
      }
}

// ---------------- fused scan (blocks 0..78) + xw (79..391) ----------------
__global__ __launch_bounds__(256) void k_scan_xw(const int* __restrict__ cnt, int* __restrict__ offset,
                                                 int* __restrict__ total, float* __restrict__ dis,
                                                 const float* __restrict__ topo, const float* __restrict__ gcn_w,
                                                 __bf16* __restrict__ xws) {
  __shared__ f32x4 w4[4096];             // 64 KB: xw weights [d(128)][jq(32)]; scan reuses as int scratch
  __shared__ int sbase;
  const int tid = threadIdx.x;
  if (blockIdx.x < 79) {
    int* red = (int*)w4;
    const int n = blockIdx.x * 256 + tid;
    const int v = (n < NNODE) ? cnt[n] : 0;
    red[tid] = v; __syncthreads();
    for (int d = 1; d < 256; d <<= 1) {
      const int t = (tid >= d) ? red[tid - d] : 0;
      __syncthreads();
      red[tid] += t;
      __syncthreads();
    }
    if (tid == 255) sbase = atomicAdd(total, red[255]);
    __syncthreads();
    if (n < NNODE) {
      offset[n] = sbase + red[tid] - v;
      dis[n] = rsqrtf((float)(v + 1));
    }
  } else {
    const f32x4* gw4 = (const f32x4*)gcn_w;
    for (int i = tid; i < 4096; i += 256) w4[i] = gw4[i];
    __syncthreads();
    const int n0 = (blockIdx.x - 79) * 64;
    const int jq = tid & 31, ns = tid >> 5;          // 8 nodes per pass
    for (int pass = 0; pass < 8; ++pass) {
      const int n = n0 + pass * 8 + ns;
      if (n >= NNODE) break;
      const f32x4* tr4 = (const f32x4*)(topo + (size_t)n * 128);
      f32x4 a = {0.f, 0.f, 0.f, 0.f};
      for (int d4 = 0; d4 < 32; ++d4) {
        const f32x4 t = tr4[d4];
        const int base = (d4 << 7) + jq;             // (d4*4)*32 + jq
        #pragma unroll
        for (int m = 0; m < 4; ++m) {
          const f32x4 w = w4[base + m * 32];
          #pragma unroll
          for (int k = 0; k < 4; ++k) a[k] += t[m] * w[k];
        }
      }
      const float dn = rsqrtf((float)(cnt[n] + 1));
      bf16x4 o;
      #pragma unroll
      for (int k = 0; k < 4; ++k) o[k] = (__bf16)(a[k] * dn);
      ((bf16x4*)xws)[(size_t)n * 32 + jq] = o;
    }
  }
}

__global__ void k_bucket(const int* __restrict__ src, const int* __restrict__ dst,
                         const int* __restrict__ offset, int* __restrict__ fill,
                         int* __restrict__ sorted_src) {
  const int e = blockIdx.x * 256 + threadIdx.x;
  if (e >= NEDGE) return;
  const int t = dst[e];
  const int pos = atomicAdd(&fill[t], 1);
  sorted_src[offset[t] + pos] = src[e];
}

// ---------------- GCN gather + fused global-max-pool ----------------
// h[n] = leaky(b + dn*(xws[n] + sum_e xws[src_e]))   [xws pre-scaled by dis]
__global__ __launch_bounds__(256) void k_gather(const int* __restrict__ sorted_src,
                                                const int* __restrict__ offset, const int* __restrict__ cnt,
                                                const float* __restrict__ dis, const __bf16* __restrict__ xws,
                                                const float* __restrict__ gcn_b, const int* __restrict__ batch,
                                                float* __restrict__ pooled_t) {
  __shared__ float hred[4][128];
  __shared__ int hg[4];
  const int wave = threadIdx.x >> 6, lane = threadIdx.x & 63;
  const int n = blockIdx.x * 4 + wave;               // grid 5000 -> n < 20000
  const int slot = lane >> 4, l16 = lane & 15;       // 4 edge slots x 16 dim-groups
  const int e0 = offset[n], ne = cnt[n];
  const bf16x8* x8 = (const bf16x8*)xws;             // row stride 16 (128 dims / 8)
  float a[8];
  if (slot == 0) {
    const bf16x8 v = x8[(size_t)n * 16 + l16];       // self term == xws[n] exactly
    #pragma unroll
    for (int k = 0; k < 8; ++k) a[k] = (float)v[k];
  } else {
    #pragma unroll
    for (int k = 0; k < 8; ++k) a[k] = 0.f;
  }
  for (int e = slot; e < ne; e += 4) {
    const int s = sorted_src[e0 + e];
    const bf16x8 v = x8[(size_t)s * 16 + l16];
    #pragma unroll
    for (int k = 0; k < 8; ++k) a[k] += (float)v[k];
  }
  #pragma unroll
  for (int k = 0; k < 8; ++k) {
    a[k] += __shfl_xor(a[k], 16, 64);
    a[k] += __shfl_xor(a[k], 32, 64);
  }
  if (lane == 0) hg[wave] = batch[n];
  if (slot == 0) {
    const float dn = dis[n];
    #pragma unroll
    for (int k = 0; k < 8; ++k) {
      float t = gcn_b[(l16 << 3) + k] + dn * a[k];
      hred[wave][(l16 << 3) + k] = t >= 0.f ? t : 0.2f * t;
    }
  }
  __syncthreads();
  const int tid = threadIdx.x;
  if (tid < 128) {
    const int g0 = hg[0], g1 = hg[1], g2 = hg[2], g3 = hg[3];
    if (g0 == g1 && g1 == g2 && g2 == g3) {          // common case (sorted batch, ~312-node runs)
      const float m = fmaxf(fmaxf(hred[0][tid], hred[1][tid]), fmaxf(hred[2][tid], hred[3][tid]));
      atomicMaxF(&pooled_t[g0 * 128 + tid], m);
    } else {
      atomicMaxF(&pooled_t[g0 * 128 + tid], hred[0][tid]);
      atomicMaxF(&pooled_t[g1 * 128 + tid], hred[1][tid]);
      atomicMaxF(&pooled_t[g2 * 128 + tid], hred[2][tid]);
      atomicMaxF(&pooled_t[g3 * 128 + tid], hred[3][tid]);
    }
  }
}

// ---------------- merged FC epilogue: blocks 0..63 vision, 64..127 topo ----------------
__global__ __launch_bounds__(256) void k_fc(const float* __restrict__ pooled_v, const float* __restrict__ fcv_w,
                                            const float* __restrict__ fcv_b,
                                            const float* __restrict__ pooled_t, const float* __restrict__ fct_w,
                                            const float* __restrict__ fct_b,
                                            const float* __restrict__ inv_sigma, float* __restrict__ out) {
  const int tid = threadIdx.x;
  if (blockIdx.x < 64) {
    __shared__ f32x4 xr[128];
    const int b = blockIdx.x;
    if (tid < 128) xr[tid] = ((const f32x4*)pooled_v)[b * 128 + tid];
    __syncthreads();
    const f32x4* wr = (const f32x4*)(fcv_w + (size_t)tid * 512);
    f32x4 a4 = {0.f, 0.f, 0.f, 0.f};
    for (int f = 0; f < 128; ++f) {
      const f32x4 x = xr[f];
      const f32x4 w = wr[f];
      #pragma unroll
      for (int k = 0; k < 4; ++k) a4[k] += x[k] * w[k];
    }
    const float a = a4[0] + a4[1] + a4[2] + a4[3];
    out[b * 256 + tid] = a * inv_sigma[1] + fcv_b[tid];
  } else {
    __shared__ f32x4 xr2[32];
    const int b = blockIdx.x - 64;
    if (tid < 32) xr2[tid] = ((const f32x4*)pooled_t)[b * 32 + tid];
    __syncthreads();
    const f32x4* wr = (const f32x4*)(fct_w + (size_t)tid * 128);
    f32x4 a4 = {0.f, 0.f, 0.f, 0.f};
    for (int f = 0; f < 32; ++f) {
      const f32x4 x = xr2[f];
      const f32x4 w = wr[f];
      #pragma unroll
      for (int k = 0; k < 4; ++k) a4[k] += x[k] * w[k];
    }
    const float a = a4[0] + a4[1] + a4[2] + a4[3];
    out[NB * 256 + b * 256 + tid] = a * inv_sigma[2] + fct_b[tid];
  }
}

extern "C" void kernel_launch(void* const* d_in, const int* in_sizes, int n_in,
                              void* d_out, int out_size, void* d_ws, size_t ws_size,
                              hipStream_t stream) {
  const float* vis    = (const float*)d_in[0];
  const float* topo   = (const float*)d_in[1];
  const int*   eidx   = (const int*)d_in[2];
  const int*   batch  = (const int*)d_in[3];
  const float* conv_w = (const float*)d_in[4];
  const float* conv_b = (const float*)d_in[5];
  const float* conv_u = (const float*)d_in[6];
  const float* fcv_w  = (const float*)d_in[7];
  const float* fcv_b  = (const float*)d_in[8];
  const float* fcv_u  = (const float*)d_in[9];
  const float* gcn_w  = (const float*)d_in[10];
  const float* gcn_b  = (const float*)d_in[11];
  const float* fct_w  = (const float*)d_in[12];
  const float* fct_b  = (const float*)d_in[13];
  const float* fct_u  = (const float*)d_in[14];
  float* out = (float*)d_out;

  char* p = (char*)d_ws;
  float* inv_sigma  = (float*)p; p += 256;
  float* sn_scratch = (float*)p; p += 1796 * 4 + 240;           // v0,v1,v2,ss (pad to 16B)
  float* pooled_v   = (float*)p; p += (size_t)NB * 512 * 4;     // 131072
  float* pooled_t   = (float*)p; p += (size_t)NB * 128 * 4;     // 32768
  int*   cnt        = (int*)p;   p += (size_t)NNODE * 4;
  int*   offset     = (int*)p;   p += (size_t)NNODE * 4;
  int*   fill       = (int*)p;   p += (size_t)NNODE * 4;
  float* dis        = (float*)p; p += (size_t)NNODE * 4;
  int*   ntotal     = (int*)p;   p += 256;
  int*   sorted_src = (int*)p;   p += (size_t)NEDGE * 4;
  __bf16* xws       = (__bf16*)p; p += (size_t)NNODE * 128 * 2 + 256;
  __hip_bfloat16* Bt2 = (__hip_bfloat16*)p; p += (size_t)147456 * 2;
  p = (char*)(((uintptr_t)p + 255) & ~(uintptr_t)255);
  __bf16* visT2 = (__bf16*)p;                                   // 64 MB + tail pad (OOB-read slack)

  // init + spectral norm (parallel 3-stage)
  hipLaunchKernelGGL(k_init,    dim3(128),  dim3(256), 0, stream, pooled_v, pooled_t, cnt, fill, sn_scratch, ntotal);
  hipLaunchKernelGGL(k_sn_v,    dim3(80),   dim3(256), 0, stream, conv_w, conv_u, fcv_w, fcv_u, fct_w, fct_u, sn_scratch);
  hipLaunchKernelGGL(k_sn_w,    dim3(160),  dim3(256), 0, stream, conv_w, fcv_w, fct_w, sn_scratch);
  hipLaunchKernelGGL(k_sn_fin,  dim3(1),    dim3(256), 0, stream, sn_scratch, inv_sigma);
  // fused prep: transpose + pack + deg
  hipLaunchKernelGGL(k_prep,    dim3(4100), dim3(256), 0, stream, vis, visT2, conv_w, inv_sigma, Bt2, eidx + NEDGE, cnt);
  // scan+xw
  hipLaunchKernelGGL(k_scan_xw, dim3(392),  dim3(256), 0, stream, cnt, offset, ntotal, dis, topo, gcn_w, xws);
  // vision head main, split for top-5 visibility; bucket standalone (R8 fusion was neutral)
  hipLaunchKernelGGL(k_conv,    dim3(32*31), dim3(256), 0, stream, (const __hip_bfloat16*)visT2, Bt2, conv_b, pooled_v, 0);
  hipLaunchKernelGGL(k_conv,    dim3(32*31), dim3(256), 0, stream, (const __hip_bfloat16*)visT2, Bt2, conv_b, pooled_v, 32);
  hipLaunchKernelGGL(k_bucket,  dim3(2500), dim3(256), 0, stream, eidx, eidx + NEDGE, offset, fill, sorted_src);
  // gather (pool fused in)
  hipLaunchKernelGGL(k_gather,  dim3(5000), dim3(256), 0, stream, sorted_src, offset, cnt, dis, xws, gcn_b, batch, pooled_t);
  // merged FC epilogue (needs pooled_v + pooled_t)
  hipLaunchKernelGGL(k_fc,      dim3(128),  dim3(256), 0, stream, pooled_v, fcv_w, fcv_b, pooled_t, fct_w, fct_b, inv_sigma, out);
}